// Round 1
// baseline (450.352 us; speedup 1.0000x reference)
//
#include <hip/hip_runtime.h>
#include <math.h>

#define T_SEQ 1152

// ---------------------------------------------------------------------------
// Kernel 0: M[b,s,m] = sum_n spatial_w[n,s] * L_norm[b,n,m]   (B x 4 x 64)
// ---------------------------------------------------------------------------
__global__ void mKernel(const float* __restrict__ L, const float* __restrict__ sw,
                        float* __restrict__ Mbuf) {
  int b = blockIdx.x, tid = threadIdx.x;   // 256 threads
  int s = tid >> 6, m = tid & 63;
  float a = 0.f;
  #pragma unroll 4
  for (int n = 0; n < 64; ++n)
    a = fmaf(sw[n * 4 + s], L[(b * 64 + n) * 64 + m], a);
  Mbuf[b * 256 + s * 64 + m] = a;
}

// ---------------------------------------------------------------------------
// Kernel A: conv(32x1, 8->8, SAME) + LayerNorm(8) + ReLU + projection by M
//   writes snn[b, t, 32]
// Block: (t-tile of 64, b). 256 threads = 16 c x 16 t-groups (4 t each).
// Loops 4 c-parts of 16 to cover all 64 channels; projection partials kept
// in registers (deterministic, no atomics).
// ---------------------------------------------------------------------------
__global__ __launch_bounds__(256, 2)
void convKernel(const float* __restrict__ X, const float* __restrict__ Kw,
                const float* __restrict__ lnS, const float* __restrict__ lnB,
                const float* __restrict__ Mbuf, float* __restrict__ snn) {
  __shared__ float Xs[8 * 16 * 95];   // [i][c][w], w = window 0..94 ; aliased by h
  __shared__ float Ks[2048];          // [kh][i][f] (same flat order as input)
  __shared__ float MsAll[256];        // [s][c] for this b
  __shared__ float lnSs[8], lnBs[8];

  const int tile = blockIdx.x;        // 0..17
  const int b    = blockIdx.y;        // 0..63
  const int tid  = threadIdx.x;       // 0..255
  const int t0   = tile * 64;

  for (int idx = tid; idx < 2048; idx += 256) Ks[idx] = Kw[idx];
  for (int idx = tid; idx < 256;  idx += 256) MsAll[idx] = Mbuf[b * 256 + idx];
  if (tid < 8) { lnSs[tid] = lnS[tid]; lnBs[tid] = lnB[tid]; }

  const int cL = tid & 15;            // local channel
  const int tg = tid >> 4;            // 0..15, each owns 4 output t's
  float sacc[8];
  #pragma unroll
  for (int k = 0; k < 8; ++k) sacc[k] = 0.f;

  float* hS = Xs;                     // h region aliases Xs (stride 516 per c)

  #pragma unroll 1
  for (int part = 0; part < 4; ++part) {
    __syncthreads();                  // previous phase-2 readers done
    // ---- stage X[b, t0-15 .. t0+79, part*16 + c, i] -> Xs[(i*16+c)*95 + w]
    {
      const float* xb = X + (size_t)(b * T_SEQ) * 512 + part * 128;
      for (int idx = tid; idx < 95 * 128; idx += 256) {
        int w = idx >> 7;             // 0..94
        int j = idx & 127;            // c*8 + i
        int c = j >> 3, i = j & 7;
        int tg_ = t0 - 15 + w;
        float v = 0.f;
        if (tg_ >= 0 && tg_ < T_SEQ) v = xb[(size_t)tg_ * 512 + j];
        Xs[(i * 16 + c) * 95 + w] = v;
      }
    }
    __syncthreads();

    // ---- conv: acc[ts][f], output t = t0 + tg*4 + ts
    float acc[4][8];
    #pragma unroll
    for (int ts = 0; ts < 4; ++ts)
      #pragma unroll
      for (int f = 0; f < 8; ++f) acc[ts][f] = 0.f;

    #pragma unroll 1
    for (int i = 0; i < 8; ++i) {
      const float* xrow = &Xs[(i * 16 + cL) * 95 + tg * 4];
      #pragma unroll 1
      for (int g = 0; g < 4; ++g) {
        float xw[11];
        #pragma unroll
        for (int u = 0; u < 11; ++u) xw[u] = xrow[g * 8 + u];
        #pragma unroll
        for (int u = 0; u < 8; ++u) {
          const int kh = g * 8 + u;
          const float4 k0 = *(const float4*)&Ks[kh * 64 + i * 8];
          const float4 k1 = *(const float4*)&Ks[kh * 64 + i * 8 + 4];
          #pragma unroll
          for (int ts = 0; ts < 4; ++ts) {
            float xv = xw[u + ts];
            acc[ts][0] = fmaf(xv, k0.x, acc[ts][0]);
            acc[ts][1] = fmaf(xv, k0.y, acc[ts][1]);
            acc[ts][2] = fmaf(xv, k0.z, acc[ts][2]);
            acc[ts][3] = fmaf(xv, k0.w, acc[ts][3]);
            acc[ts][4] = fmaf(xv, k1.x, acc[ts][4]);
            acc[ts][5] = fmaf(xv, k1.y, acc[ts][5]);
            acc[ts][6] = fmaf(xv, k1.z, acc[ts][6]);
            acc[ts][7] = fmaf(xv, k1.w, acc[ts][7]);
          }
        }
      }
    }
    __syncthreads();                  // all Xs reads done before h overwrite

    // ---- LayerNorm(8) + ReLU, write h to LDS (stride 516 to dodge banks)
    #pragma unroll
    for (int ts = 0; ts < 4; ++ts) {
      float mu = 0.f;
      #pragma unroll
      for (int f = 0; f < 8; ++f) mu += acc[ts][f];
      mu *= 0.125f;
      float var = 0.f;
      #pragma unroll
      for (int f = 0; f < 8; ++f) { float d = acc[ts][f] - mu; var += d * d; }
      var *= 0.125f;
      float r = 1.0f / sqrtf(var + 1e-6f);
      int tloc = tg * 4 + ts;
      #pragma unroll
      for (int f = 0; f < 8; ++f) {
        float h = (acc[ts][f] - mu) * r * lnSs[f] + lnBs[f];
        h = fmaxf(h, 0.f);
        hS[cL * 516 + tloc * 8 + f] = h;
      }
    }
    __syncthreads();

    // ---- projection partial: snn[t, s*8+f] += sum_c M[s,c] * h[c,t,f]
    #pragma unroll
    for (int k = 0; k < 8; ++k) {
      int idx = k * 256 + tid;        // 0..2047 = t*32 + (s*8+f)
      int t = idx >> 5, rr = idx & 31, s = rr >> 3, f = rr & 7;
      float v = 0.f;
      #pragma unroll
      for (int c2 = 0; c2 < 16; ++c2)
        v = fmaf(hS[c2 * 516 + t * 8 + f], MsAll[s * 64 + part * 16 + c2], v);
      sacc[k] += v;
    }
  }

  // ---- write snn tile
  #pragma unroll
  for (int k = 0; k < 8; ++k) {
    int idx = k * 256 + tid;
    int t = idx >> 5, rr = idx & 31;
    snn[((size_t)(b * T_SEQ) + t0 + t) * 32 + rr] = sacc[k];
  }
}

// ---------------------------------------------------------------------------
// Kernel B: LIF scan over T for each (b, j) chain. 64 blocks x 32 threads.
// Writes flat[b, chunk*64 + half*32 + j] and per-block spike sums.
// ---------------------------------------------------------------------------
__global__ void scanKernel(const float* __restrict__ snn, float* __restrict__ flat,
                           float* __restrict__ spkPart) {
  const int b = blockIdx.x;           // 0..63
  const int j = threadIdx.x;          // 0..31
  const float* base = snn + (size_t)b * T_SEQ * 32 + j;

  float mem1 = 0.f, mem2 = 0.f, mo = 0.f, s1 = 0.f, s2 = 0.f;
  float xs[24], xn[24];
  #pragma unroll
  for (int u = 0; u < 24; ++u) xs[u] = base[u * 32];

  for (int ch = 0; ch < 48; ++ch) {
    if (ch < 47) {
      #pragma unroll
      for (int u = 0; u < 24; ++u) xn[u] = base[((ch + 1) * 24 + u) * 32];
    }
    float aS = 0.f, aE = 0.f;
    #pragma unroll
    for (int u = 0; u < 24; ++u) {
      mem1 = mem1 * 0.8f + xs[u];
      float sp1 = (mem1 > 0.5f) ? 1.0f : 0.0f;
      mem1 -= sp1 * 0.5f;
      mem2 = mem2 * 0.9f + sp1;
      float sp2 = (mem2 > 0.5f) ? 1.0f : 0.0f;
      mem2 -= sp2 * 0.5f;
      mo = mo * 0.95f + sp2;
      s1 += sp1; s2 += sp2;
      if (u < 12) aS += mo; else aE += mo;
    }
    flat[b * 3072 + ch * 64 + j]      = aS / 12.0f;
    flat[b * 3072 + ch * 64 + 32 + j] = aE / 12.0f;
    if (ch < 47) {
      #pragma unroll
      for (int u = 0; u < 24; ++u) xs[u] = xn[u];
    }
  }
  // reduce spike sums over 32 lanes
  for (int off = 16; off > 0; off >>= 1) {
    s1 += __shfl_down(s1, off, 32);
    s2 += __shfl_down(s2, off, 32);
  }
  if (j == 0) { spkPart[b * 2] = s1; spkPart[b * 2 + 1] = s2; }
}

// ---------------------------------------------------------------------------
// Kernel C: y = gelu(flat @ W1 + b1); logits = y @ W2 + b2 ; firing rate.
// 65 blocks x 256 threads (block 64 does the firing rate).
// ---------------------------------------------------------------------------
__global__ void mlpKernel(const float* __restrict__ flat, const float* __restrict__ W1,
                          const float* __restrict__ b1, const float* __restrict__ W2,
                          const float* __restrict__ b2, const float* __restrict__ spkPart,
                          float* __restrict__ out) {
  if (blockIdx.x == 64) {
    if (threadIdx.x == 0) {
      float s1 = 0.f, s2 = 0.f;
      for (int i = 0; i < 64; ++i) { s1 += spkPart[2 * i]; s2 += spkPart[2 * i + 1]; }
      out[256] = (s1 + s2) * 0.5f / (64.0f * 1152.0f * 32.0f);
    }
    return;
  }
  const int b = blockIdx.x;
  const int tid = threadIdx.x;        // 256
  const int u = tid & 31, kc = tid >> 5;
  __shared__ float red[256];
  __shared__ float ys[32];
  float p = 0.f;
  const int kbeg = kc * 384, kend = kbeg + 384;
  #pragma unroll 4
  for (int k = kbeg; k < kend; ++k)
    p = fmaf(flat[b * 3072 + k], W1[k * 32 + u], p);
  red[tid] = p;
  __syncthreads();
  if (kc == 0) {
    float y = b1[u];
    #pragma unroll
    for (int q = 0; q < 8; ++q) y += red[q * 32 + u];
    float y3 = y * y * y;
    float th = tanhf(0.7978845608028654f * (y + 0.044715f * y3));
    ys[u] = 0.5f * y * (1.0f + th);
  }
  __syncthreads();
  if (tid < 4) {
    float accv = b2[tid];
    #pragma unroll
    for (int q = 0; q < 32; ++q) accv = fmaf(ys[q], W2[q * 4 + tid], accv);
    out[b * 4 + tid] = accv;
  }
}

// ---------------------------------------------------------------------------
extern "C" void kernel_launch(void* const* d_in, const int* in_sizes, int n_in,
                              void* d_out, int out_size, void* d_ws, size_t ws_size,
                              hipStream_t stream) {
  const float* L   = (const float*)d_in[0];
  const float* X   = (const float*)d_in[1];
  // d_in[2] = deterministic (unused)
  const float* Kw  = (const float*)d_in[3];
  const float* lnS = (const float*)d_in[4];
  const float* lnB = (const float*)d_in[5];
  const float* sw  = (const float*)d_in[6];
  const float* W1  = (const float*)d_in[7];
  const float* b1  = (const float*)d_in[8];
  const float* W2  = (const float*)d_in[9];
  const float* b2  = (const float*)d_in[10];

  float* ws   = (float*)d_ws;
  float* Mbuf = ws;                       // 64*4*64      = 16384
  float* snn  = Mbuf + 16384;             // 64*1152*32   = 2359296
  float* flat = snn + 2359296;            // 64*3072      = 196608
  float* spk  = flat + 196608;            // 128
  float* out  = (float*)d_out;

  mKernel<<<64, 256, 0, stream>>>(L, sw, Mbuf);
  convKernel<<<dim3(18, 64), 256, 0, stream>>>(X, Kw, lnS, lnB, Mbuf, snn);
  scanKernel<<<64, 32, 0, stream>>>(snn, flat, spk);
  mlpKernel<<<65, 256, 0, stream>>>(flat, W1, b1, W2, b2, spk, out);
}